// Round 4
// baseline (658.040 us; speedup 1.0000x reference)
//
#include <hip/hip_runtime.h>
#include <stdint.h>

typedef _Float16 half8 __attribute__((ext_vector_type(8)));
typedef float float4v __attribute__((ext_vector_type(4)));

// Problem constants
constexpr int kN = 100000;   // nodes
constexpr int kE = 1600000;  // edges
constexpr int kP = 500000;   // pairs
constexpr int NBS = (kN + 255) / 256;  // scan blocks = 391
constexpr int CT3 = kN / 16;           // 6250 conv wave-tiles (16 nodes, exact)
constexpr int DT2 = kP / 32;           // 15625 decoder wave-tiles (32 pairs, exact)
constexpr int PBINS = 3125;            // pair-sort buckets: a>>5, a<100000
constexpr int PBINS_PAD = 3328;        // padded for alignment/memset
constexpr int PHB = (kP + 255) / 256;  // 1954 blocks for pair hist/scatter
constexpr int EFB = (kE + 255) / 256;  // 6250 blocks for edge fill

// ---------------------------------------------------------------------------
// Fused prep: deg+slot histogram, x->fp16, weights->fp16 planes, pair-hist.
// Blocks [0,6250): deg_slot; [6250,12500): cvt_x; [12500,12852): cvt_w;
// [12852,12852+1954): pair-sort histogram (key = a >> 5).
// ---------------------------------------------------------------------------
__global__ void prep_kernel(
    const int* __restrict__ dst, int* __restrict__ deg, int* __restrict__ slot,
    const float* __restrict__ x, _Float16* __restrict__ xh,
    const float* __restrict__ W1l, const float* __restrict__ W1r,
    const float* __restrict__ W2l, const float* __restrict__ W2r,
    const float* __restrict__ Wm1, const float* __restrict__ Wm2,
    _Float16* __restrict__ CW1h, _Float16* __restrict__ CW1e,
    _Float16* __restrict__ CW2h, _Float16* __restrict__ CW2e,
    _Float16* __restrict__ M1h,  _Float16* __restrict__ M2h,
    const int* __restrict__ ep, int* __restrict__ phist, int* __restrict__ pslot)
{
    const int b = blockIdx.x;
    if (b < 6250) {
        const int e = b * 256 + threadIdx.x;
        if (e < kE) slot[e] = atomicAdd(&deg[dst[e]], 1);
    } else if (b < 12500) {
        const int i = ((b - 6250) * 256 + threadIdx.x) * 8;
        if (i >= kN * 128) return;
        const float4 a = *(const float4*)&x[i];
        const float4 bb = *(const float4*)&x[i + 4];
        half8 v;
        v[0] = (_Float16)a.x;  v[1] = (_Float16)a.y;  v[2] = (_Float16)a.z;  v[3] = (_Float16)a.w;
        v[4] = (_Float16)bb.x; v[5] = (_Float16)bb.y; v[6] = (_Float16)bb.z; v[7] = (_Float16)bb.w;
        *(half8*)&xh[i] = v;
    } else if (b < 12852) {
        const int i = (b - 12500) * 256 + threadIdx.x;
        if (i < 32768) {
            const int o = i >> 8, k = i & 255;
            const float w = (k < 128) ? W1l[o * 128 + k] : W1r[o * 128 + k - 128];
            const _Float16 h = (_Float16)w;
            CW1h[i] = h; CW1e[i] = (_Float16)(w - (float)h);
        } else if (i < 65536) {
            const int j = i - 32768;
            const int o = j >> 8, k = j & 255;
            const float w = (k < 128) ? W2l[o * 128 + k] : W2r[o * 128 + k - 128];
            const _Float16 h = (_Float16)w;
            CW2h[j] = h; CW2e[j] = (_Float16)(w - (float)h);
        } else if (i < 81920) {
            const int j = i - 65536;
            M1h[j] = (_Float16)Wm1[j];
        } else if (i < 90112) {
            const int j = i - 81920;
            M2h[j] = (_Float16)Wm2[j];
        }
    } else {
        const int i = (b - 12852) * 256 + threadIdx.x;
        if (i < kP) {
            const int a = ep[(size_t)i * 2];
            pslot[i] = atomicAdd(&phist[a >> 5], 1);
        }
    }
}

// ---------------------------------------------------------------------------
// Pair-sort: exclusive scan over PBINS buckets (1 block). Scatter is folded
// into fill2_kernel (zero extra dispatch).
// ---------------------------------------------------------------------------
__global__ void psort_scan(const int* __restrict__ phist, int* __restrict__ pbase) {
    __shared__ int sm[1024];
    const int t = threadIdx.x;
    int v[4];
    int s = 0;
#pragma unroll
    for (int r = 0; r < 4; r++) {
        const int bi = t * 4 + r;
        v[r] = (bi < PBINS) ? phist[bi] : 0;
        s += v[r];
    }
    sm[t] = s;
    __syncthreads();
    for (int d = 1; d < 1024; d <<= 1) {
        int u = (t >= d) ? sm[t - d] : 0;
        __syncthreads();
        sm[t] += u;
        __syncthreads();
    }
    int excl = sm[t] - s;
#pragma unroll
    for (int r = 0; r < 4; r++) {
        const int bi = t * 4 + r;
        if (bi < PBINS) pbase[bi] = excl;
        excl += v[r];
    }
}

// ---------------------------------------------------------------------------
// Scan + atomic-free CSR fill
// ---------------------------------------------------------------------------
__global__ void scan_block_sums(const int* __restrict__ deg, int* __restrict__ bsum) {
    __shared__ int red[256];
    int t = threadIdx.x;
    int i = blockIdx.x * 256 + t;
    red[t] = (i < kN) ? deg[i] : 0;
    __syncthreads();
    for (int s = 128; s > 0; s >>= 1) {
        if (t < s) red[t] += red[t + s];
        __syncthreads();
    }
    if (t == 0) bsum[blockIdx.x] = red[0];
}

__global__ void scan_bsums(const int* __restrict__ bsum, int* __restrict__ boff) {
    __shared__ int sm[512];
    int t = threadIdx.x;
    int orig = (t < NBS) ? bsum[t] : 0;
    sm[t] = orig;
    __syncthreads();
    for (int d = 1; d < 512; d <<= 1) {
        int u = (t >= d) ? sm[t - d] : 0;
        __syncthreads();
        sm[t] += u;
        __syncthreads();
    }
    if (t < NBS) boff[t] = sm[t] - orig;  // exclusive
}

__global__ void scan_write(const int* __restrict__ deg, const int* __restrict__ boff,
                           int* __restrict__ row_start) {
    __shared__ int sm[256];
    int t = threadIdx.x;
    int i = blockIdx.x * 256 + t;
    int v = (i < kN) ? deg[i] : 0;
    sm[t] = v;
    __syncthreads();
    for (int d = 1; d < 256; d <<= 1) {
        int u = (t >= d) ? sm[t - d] : 0;
        __syncthreads();
        sm[t] += u;
        __syncthreads();
    }
    int excl = sm[t] - v + boff[blockIdx.x];
    if (i < kN) row_start[i] = excl;
    if (i == kN - 1) row_start[kN] = excl + v;
}

// fill2 + pair-scatter fused: blocks [0,6250) fill CSR srcs; [6250,6250+1954)
// scatter pairs into sorted order.
__global__ void fill2_kernel(const int* __restrict__ src, const int* __restrict__ dst,
                             const int* __restrict__ row_start,
                             const int* __restrict__ slot, int* __restrict__ srcs,
                             const int* __restrict__ ep,
                             const int* __restrict__ pbase,
                             const int* __restrict__ pslot,
                             int2* __restrict__ spair, int* __restrict__ sidx) {
    const int b = blockIdx.x;
    if (b < EFB) {
        const int e = b * 256 + threadIdx.x;
        if (e < kE) srcs[row_start[dst[e]] + slot[e]] = src[e];
    } else {
        const int i = (b - EFB) * 256 + threadIdx.x;
        if (i < kP) {
            const int a = ep[(size_t)i * 2];
            const int bb = ep[(size_t)i * 2 + 1];
            const int pos = pbase[a >> 5] + pslot[i];
            spair[pos] = make_int2(a, bb);
            sidx[pos] = i;
        }
    }
}

// ---------------------------------------------------------------------------
// Single-wave fused SAGEConv, 16 nodes/block (64 threads), no __syncthreads.
// EXACT R0-proven config (145 us): wave packing was shown neutral-to-negative
// (R1 spilled, R2 no-spill still 164 us) -- the kernel is pinned by a chip-
// level random-fetch-line rate (~1.33 TB/s) invariant across occupancy.
// Gather: per 16-lane group, 16 idx prefetched coalesced; 16 row loads
// batched in registers with a sched_barrier(0) pinning ALL loads before the
// consume. (64,4) bound = 128-reg cap.
// MFMA: M=16, K=256 [mean|root], weights hi+lo from L2.
// LDS: [16][136] fp16 = 4352 B/block.
// ---------------------------------------------------------------------------
template <bool RELU>
__global__ __launch_bounds__(64, 4) void conv_mfma(
    const _Float16* __restrict__ xin,
    const int* __restrict__ row_start,
    const int* __restrict__ srcs,
    const _Float16* __restrict__ Wh,  // [128][256]
    const _Float16* __restrict__ We,  // [128][256]
    const float* __restrict__ bias,
    _Float16* __restrict__ out)
{
    __shared__ __align__(16) _Float16 stg[16 * 136];
    const int l = threadIdx.x & 63;
    const int p = l & 15;
    const int q = l >> 4;
    const int tile = blockIdx.x;
    const int c = p * 8;
    const int lbase = l & 48;

    // Group's 4 nodes: n_s = tile*16 + s*4 + q
    int j0[4], j1[4];
#pragma unroll
    for (int s = 0; s < 4; s++) {
        const int n = tile * 16 + s * 4 + q;
        j0[s] = row_start[n];
        j1[s] = row_start[n + 1];
    }
    // Prefetch first 16 neighbor idx per node (srcs padded; guarded).
    int idx16[4];
#pragma unroll
    for (int s = 0; s < 4; s++) {
        const int tA = j0[s] + p;
        const int v  = srcs[tA];
        idx16[s] = (tA < j1[s]) ? v : 0;
    }

#pragma unroll
    for (int s = 0; s < 4; s++) {
        const int cnt = j1[s] - j0[s];
        float facc[8];
#pragma unroll
        for (int u = 0; u < 8; u++) facc[u] = 0.f;

        for (int jc = j0[s]; jc < j1[s]; jc += 16) {
            int myidx;
            if (jc == j0[s]) {
                myidx = idx16[s];
            } else {
                const int tB = jc + p;
                const int v  = srcs[tB];  // padded, safe
                myidx = (tB < j1[s]) ? v : 0;
            }
            half8 rows[16];
#pragma unroll
            for (int i = 0; i < 16; i++) {
                const int sidx = __shfl(myidx, lbase + i);
                rows[i] = *(const half8*)&xin[(size_t)sidx * 128 + c];
            }
            // Pin: every row load issued before any consume (16 KB/wave in flight)
            __builtin_amdgcn_sched_barrier(0);
            const int rem = j1[s] - jc;
#pragma unroll
            for (int i = 0; i < 16; i++) {
                if (i < rem) {
#pragma unroll
                    for (int u = 0; u < 8; u++) facc[u] += (float)rows[i][u];
                }
            }
        }
        const float inv = 1.0f / (float)(cnt > 1 ? cnt : 1);
        half8 hv;
#pragma unroll
        for (int u = 0; u < 8; u++) hv[u] = (_Float16)(facc[u] * inv);
        *(half8*)&stg[(s * 4 + q) * 136 + c] = hv;
    }

    // Root rows, frag-direct (consecutive rows -> fully coalesced)
    half8 rt[4];
#pragma unroll
    for (int kt = 0; kt < 4; kt++)
        rt[kt] = *(const half8*)&xin[(size_t)(tile * 16 + p) * 128 + kt * 32 + q * 8];

    // A-frags for mean half (same-wave DS in-order)
    half8 am[4];
#pragma unroll
    for (int kt = 0; kt < 4; kt++)
        am[kt] = *(const half8*)&stg[p * 136 + kt * 32 + q * 8];

    // MFMA: D[16][128] = A[16][256] @ CW[128][256]^T (hi+lo)
    float4v acc[8];
#pragma unroll
    for (int nt = 0; nt < 8; nt++) {
        const float b = bias[nt * 16 + p];
        acc[nt][0] = b; acc[nt][1] = b; acc[nt][2] = b; acc[nt][3] = b;
    }
#pragma unroll
    for (int kt = 0; kt < 8; kt++) {
        const half8 a = (kt < 4) ? am[kt] : rt[kt - 4];
#pragma unroll
        for (int nt = 0; nt < 8; nt++) {
            const int widx = (nt * 16 + p) * 256 + kt * 32 + q * 8;
            const half8 bh = *(const half8*)&Wh[widx];
            const half8 be = *(const half8*)&We[widx];
            acc[nt] = __builtin_amdgcn_mfma_f32_16x16x32_f16(a, bh, acc[nt], 0, 0, 0);
            acc[nt] = __builtin_amdgcn_mfma_f32_16x16x32_f16(a, be, acc[nt], 0, 0, 0);
        }
    }

    // Epilogue: C-layout -> LDS slice -> coalesced row-major store
#pragma unroll
    for (int nt = 0; nt < 8; nt++)
#pragma unroll
        for (int r = 0; r < 4; r++) {
            float v = acc[nt][r];
            if (RELU) v = fmaxf(v, 0.f);
            stg[(q * 4 + r) * 136 + nt * 16 + p] = (_Float16)v;
        }
    {
        const int row = l >> 2;
        const int c2  = (l & 3) * 8;
#pragma unroll
        for (int i = 0; i < 4; i++)
            *(half8*)&out[(size_t)(tile * 16 + row) * 128 + i * 32 + c2] =
                *(const half8*)&stg[row * 136 + i * 32 + c2];
    }
}

// ---------------------------------------------------------------------------
// Single-wave fused decoder over SORTED pairs, 32 pairs/block (64 threads),
// NATURAL block order (no XCD swizzle). Rationale: ~2700 blocks are resident
// concurrently and dispatch roughly in blockIdx order, so the active a-range
// is a sliding window of ~5k nodes = 1.4 MB -- L2-resident on EVERY XCD under
// ANY block->XCD mapping. (The R3 swizzle assumed round-robin mapping; if the
// real mapping is chunked it destroyed locality. Natural order is robust.)
// b-side stays random. Output scattered back via sidx (outv 2 MB, L2-resident).
// LDS: [32][136] fp16 = 8704 B/block.
// ---------------------------------------------------------------------------
__global__ __launch_bounds__(64, 4) void decoder_mfma(
    const _Float16* __restrict__ z,
    const int2* __restrict__ spair,
    const int* __restrict__ sidx,
    const _Float16* __restrict__ M1h, const float* __restrict__ bm1,
    const _Float16* __restrict__ M2h, const float* __restrict__ bm2,
    const float* __restrict__ Wm3, const float* __restrict__ bm3,
    float* __restrict__ outv)
{
    __shared__ __align__(16) _Float16 buf[32 * 136];
    const int l = threadIdx.x & 63;
    const int p = l & 15;
    const int q = l >> 4;
    const int tile = blockIdx.x;
    const int c = p * 8;

    // P1: hp = z[a]*z[b]; batch all idx loads, then all row loads (2 epochs)
    int2 ab[8];
#pragma unroll
    for (int it = 0; it < 8; it++)
        ab[it] = spair[tile * 32 + it * 4 + q];
    half8 za[8], zb[8];
#pragma unroll
    for (int it = 0; it < 8; it++) {
        za[it] = *(const half8*)&z[(size_t)ab[it].x * 128 + c];
        zb[it] = *(const half8*)&z[(size_t)ab[it].y * 128 + c];
    }
    __builtin_amdgcn_sched_barrier(0);
#pragma unroll
    for (int it = 0; it < 8; it++)
        *(half8*)&buf[(it * 4 + q) * 136 + c] = za[it] * zb[it];

    // L1: y1 = relu(hp @ M1^T + bm1), M=32, N=128, K=128
    half8 a1[2][4];
#pragma unroll
    for (int m = 0; m < 2; m++)
#pragma unroll
        for (int kt = 0; kt < 4; kt++)
            a1[m][kt] = *(const half8*)&buf[(m * 16 + p) * 136 + kt * 32 + q * 8];

    float4v acc1[2][8];
#pragma unroll
    for (int nt = 0; nt < 8; nt++) {
        const float b = bm1[nt * 16 + p];
#pragma unroll
        for (int m = 0; m < 2; m++) {
            acc1[m][nt][0] = b; acc1[m][nt][1] = b; acc1[m][nt][2] = b; acc1[m][nt][3] = b;
        }
    }
#pragma unroll
    for (int kt = 0; kt < 4; kt++)
#pragma unroll
        for (int nt = 0; nt < 8; nt++) {
            const half8 bh = *(const half8*)&M1h[(nt * 16 + p) * 128 + kt * 32 + q * 8];
            acc1[0][nt] = __builtin_amdgcn_mfma_f32_16x16x32_f16(a1[0][kt], bh, acc1[0][nt], 0, 0, 0);
            acc1[1][nt] = __builtin_amdgcn_mfma_f32_16x16x32_f16(a1[1][kt], bh, acc1[1][nt], 0, 0, 0);
        }

    // y1 -> LDS (same-wave order: a1 reads already done)
#pragma unroll
    for (int m = 0; m < 2; m++)
#pragma unroll
        for (int nt = 0; nt < 8; nt++)
#pragma unroll
            for (int r = 0; r < 4; r++)
                buf[(m * 16 + q * 4 + r) * 136 + nt * 16 + p] =
                    (_Float16)fmaxf(acc1[m][nt][r], 0.f);

    // L2: y2 = relu(y1 @ M2^T + bm2), N=64, K=128
    half8 a2[2][4];
#pragma unroll
    for (int m = 0; m < 2; m++)
#pragma unroll
        for (int kt = 0; kt < 4; kt++)
            a2[m][kt] = *(const half8*)&buf[(m * 16 + p) * 136 + kt * 32 + q * 8];

    float4v acc2[2][4];
#pragma unroll
    for (int nt = 0; nt < 4; nt++) {
        const float b = bm2[nt * 16 + p];
#pragma unroll
        for (int m = 0; m < 2; m++) {
            acc2[m][nt][0] = b; acc2[m][nt][1] = b; acc2[m][nt][2] = b; acc2[m][nt][3] = b;
        }
    }
#pragma unroll
    for (int kt = 0; kt < 4; kt++)
#pragma unroll
        for (int nt = 0; nt < 4; nt++) {
            const half8 bh = *(const half8*)&M2h[(nt * 16 + p) * 128 + kt * 32 + q * 8];
            acc2[0][nt] = __builtin_amdgcn_mfma_f32_16x16x32_f16(a2[0][kt], bh, acc2[0][nt], 0, 0, 0);
            acc2[1][nt] = __builtin_amdgcn_mfma_f32_16x16x32_f16(a2[1][kt], bh, acc2[1][nt], 0, 0, 0);
        }

    // L3: out = relu(y2) . Wm3 + bm3, scattered back through the sort perm
    float wm3v[4];
#pragma unroll
    for (int nt = 0; nt < 4; nt++) wm3v[nt] = Wm3[nt * 16 + p];
    const float b3 = bm3[0];
#pragma unroll
    for (int m = 0; m < 2; m++) {
        float part[4];
#pragma unroll
        for (int r = 0; r < 4; r++) part[r] = 0.f;
#pragma unroll
        for (int nt = 0; nt < 4; nt++)
#pragma unroll
            for (int r = 0; r < 4; r++)
                part[r] += fmaxf(acc2[m][nt][r], 0.f) * wm3v[nt];
#pragma unroll
        for (int s = 1; s <= 8; s <<= 1)
#pragma unroll
            for (int r = 0; r < 4; r++) part[r] += __shfl_xor(part[r], s);
        if (p == 0) {
            const int base = tile * 32 + m * 16 + q * 4;
            const int4 oi = *(const int4*)&sidx[base];
            outv[oi.x] = part[0] + b3;
            outv[oi.y] = part[1] + b3;
            outv[oi.z] = part[2] + b3;
            outv[oi.w] = part[3] + b3;
        }
    }
}

// ---------------------------------------------------------------------------
extern "C" void kernel_launch(void* const* d_in, const int* in_sizes, int n_in,
                              void* d_out, int out_size, void* d_ws, size_t ws_size,
                              hipStream_t stream) {
    const float* x   = (const float*)d_in[0];
    const int*   src = (const int*)d_in[1];
    const int*   dst = src + kE;
    const int*   ep  = (const int*)d_in[2];
    const float* W1l = (const float*)d_in[3];
    const float* b1l = (const float*)d_in[4];
    const float* W1r = (const float*)d_in[5];
    const float* W2l = (const float*)d_in[6];
    const float* b2l = (const float*)d_in[7];
    const float* W2r = (const float*)d_in[8];
    const float* Wm1 = (const float*)d_in[9];
    const float* bm1 = (const float*)d_in[10];
    const float* Wm2 = (const float*)d_in[11];
    const float* bm2 = (const float*)d_in[12];
    const float* Wm3 = (const float*)d_in[13];
    const float* bm3 = (const float*)d_in[14];
    float* outv = (float*)d_out;

    char* ws = (char*)d_ws;
    size_t off = 0;
    auto alloc = [&](size_t bytes) -> void* {
        void* p = ws + off;
        off += bytes;
        off = (off + 255) & ~(size_t)255;
        return p;
    };
    int*      deg       = (int*)alloc((size_t)kN * 4);
    int*      phist     = (int*)alloc((size_t)PBINS_PAD * 4);  // right after deg: one memset
    int*      row_start = (int*)alloc((size_t)(kN + 1) * 4);
    int*      slot      = (int*)alloc((size_t)kE * 4);
    int*      bsum      = (int*)alloc(512 * 4);
    int*      boff      = (int*)alloc(512 * 4);
    int*      pbase     = (int*)alloc((size_t)PBINS_PAD * 4);
    int*      pslot     = (int*)alloc((size_t)kP * 4);
    int2*     spair     = (int2*)alloc((size_t)kP * 8);
    int*      sidx      = (int*)alloc((size_t)kP * 4);
    int*      srcs      = (int*)alloc((size_t)(kE + 64) * 4);  // padded
    _Float16* xh        = (_Float16*)alloc((size_t)kN * 128 * 2);
    _Float16* hh        = (_Float16*)alloc((size_t)kN * 128 * 2);
    _Float16* zh        = (_Float16*)alloc((size_t)kN * 128 * 2);
    _Float16* CW1h      = (_Float16*)alloc(128 * 256 * 2);
    _Float16* CW1e      = (_Float16*)alloc(128 * 256 * 2);
    _Float16* CW2h      = (_Float16*)alloc(128 * 256 * 2);
    _Float16* CW2e      = (_Float16*)alloc(128 * 256 * 2);
    _Float16* M1h       = (_Float16*)alloc(128 * 128 * 2);
    _Float16* M2h       = (_Float16*)alloc(64 * 128 * 2);

    // One memset covers deg + phist (allocated adjacently)
    const size_t z0 = (size_t)((char*)(phist + PBINS_PAD) - (char*)deg);
    hipMemsetAsync(deg, 0, z0, stream);

    // Fused prep (histogram+slot, cvt_x, cvt_w, pair-hist)
    prep_kernel<<<12852 + PHB, 256, 0, stream>>>(dst, deg, slot, x, xh,
                                                 W1l, W1r, W2l, W2r, Wm1, Wm2,
                                                 CW1h, CW1e, CW2h, CW2e, M1h, M2h,
                                                 ep, phist, pslot);
    // Pair-bucket scan (tiny) + CSR scan chain
    psort_scan<<<1, 1024, 0, stream>>>(phist, pbase);
    scan_block_sums<<<NBS, 256, 0, stream>>>(deg, bsum);
    scan_bsums<<<1, 512, 0, stream>>>(bsum, boff);
    scan_write<<<NBS, 256, 0, stream>>>(deg, boff, row_start);
    // Fused CSR fill + pair scatter (one dispatch)
    fill2_kernel<<<EFB + PHB, 256, 0, stream>>>(src, dst, row_start, slot, srcs,
                                                ep, pbase, pslot, spair, sidx);

    // Two SAGEConv layers (single-wave blocks, pinned 16-row batches)
    conv_mfma<true><<<CT3, 64, 0, stream>>>(xh, row_start, srcs, CW1h, CW1e, b1l, hh);
    conv_mfma<false><<<CT3, 64, 0, stream>>>(hh, row_start, srcs, CW2h, CW2e, b2l, zh);

    // Fused decoder over sorted pairs (natural order, sliding a-window in L2)
    decoder_mfma<<<DT2, 64, 0, stream>>>(
        zh, spair, sidx, M1h, bm1, M2h, bm2, Wm3, bm3, outv);
}

// Round 6
// 604.162 us; speedup vs baseline: 1.0892x; 1.0892x over previous
//
#include <hip/hip_runtime.h>
#include <stdint.h>

typedef _Float16 half8 __attribute__((ext_vector_type(8)));
typedef float float4v __attribute__((ext_vector_type(4)));
typedef float floatx4 __attribute__((ext_vector_type(4)));
typedef int intx2 __attribute__((ext_vector_type(2)));

// Problem constants
constexpr int kN = 100000;   // nodes
constexpr int kE = 1600000;  // edges
constexpr int kP = 500000;   // pairs
constexpr int NBS = (kN + 255) / 256;  // scan blocks = 391
constexpr int CT3 = kN / 16;           // 6250 conv wave-tiles (16 nodes, exact)
constexpr int DT2 = kP / 32;           // 15625 decoder wave-tiles (32 pairs, exact)

// ---------------------------------------------------------------------------
// Fused prep: deg+slot histogram, x->fp16, weights->fp16 planes (one dispatch)
// Blocks [0,6250): deg_slot; [6250,12500): cvt_x; [12500,12852): cvt_w.
// R3/R4 lesson: pair-sorting the decoder cost ~50us of build time and gained
// exactly zero (a-row reuse is spread across 8 incoherent XCD L2s) -- sort
// machinery removed, back to the proven R0 structure.
// ---------------------------------------------------------------------------
__global__ void prep_kernel(
    const int* __restrict__ dst, int* __restrict__ deg, int* __restrict__ slot,
    const float* __restrict__ x, _Float16* __restrict__ xh,
    const float* __restrict__ W1l, const float* __restrict__ W1r,
    const float* __restrict__ W2l, const float* __restrict__ W2r,
    const float* __restrict__ Wm1, const float* __restrict__ Wm2,
    _Float16* __restrict__ CW1h, _Float16* __restrict__ CW1e,
    _Float16* __restrict__ CW2h, _Float16* __restrict__ CW2e,
    _Float16* __restrict__ M1h,  _Float16* __restrict__ M2h)
{
    const int b = blockIdx.x;
    if (b < 6250) {
        const int e = b * 256 + threadIdx.x;
        if (e < kE) slot[e] = atomicAdd(&deg[dst[e]], 1);
    } else if (b < 12500) {
        const int i = ((b - 6250) * 256 + threadIdx.x) * 8;
        if (i >= kN * 128) return;
        // x is read exactly once -> non-temporal (don't evict useful L2 lines)
        const floatx4 a = __builtin_nontemporal_load((const floatx4*)&x[i]);
        const floatx4 bb = __builtin_nontemporal_load((const floatx4*)&x[i + 4]);
        half8 v;
        v[0] = (_Float16)a[0]; v[1] = (_Float16)a[1]; v[2] = (_Float16)a[2]; v[3] = (_Float16)a[3];
        v[4] = (_Float16)bb[0]; v[5] = (_Float16)bb[1]; v[6] = (_Float16)bb[2]; v[7] = (_Float16)bb[3];
        *(half8*)&xh[i] = v;
    } else {
        const int i = (b - 12500) * 256 + threadIdx.x;
        if (i < 32768) {
            const int o = i >> 8, k = i & 255;
            const float w = (k < 128) ? W1l[o * 128 + k] : W1r[o * 128 + k - 128];
            const _Float16 h = (_Float16)w;
            CW1h[i] = h; CW1e[i] = (_Float16)(w - (float)h);
        } else if (i < 65536) {
            const int j = i - 32768;
            const int o = j >> 8, k = j & 255;
            const float w = (k < 128) ? W2l[o * 128 + k] : W2r[o * 128 + k - 128];
            const _Float16 h = (_Float16)w;
            CW2h[j] = h; CW2e[j] = (_Float16)(w - (float)h);
        } else if (i < 81920) {
            const int j = i - 65536;
            M1h[j] = (_Float16)Wm1[j];
        } else if (i < 90112) {
            const int j = i - 81920;
            M2h[j] = (_Float16)Wm2[j];
        }
    }
}

// ---------------------------------------------------------------------------
// Scan + atomic-free CSR fill
// ---------------------------------------------------------------------------
__global__ void scan_block_sums(const int* __restrict__ deg, int* __restrict__ bsum) {
    __shared__ int red[256];
    int t = threadIdx.x;
    int i = blockIdx.x * 256 + t;
    red[t] = (i < kN) ? deg[i] : 0;
    __syncthreads();
    for (int s = 128; s > 0; s >>= 1) {
        if (t < s) red[t] += red[t + s];
        __syncthreads();
    }
    if (t == 0) bsum[blockIdx.x] = red[0];
}

__global__ void scan_bsums(const int* __restrict__ bsum, int* __restrict__ boff) {
    __shared__ int sm[512];
    int t = threadIdx.x;
    int orig = (t < NBS) ? bsum[t] : 0;
    sm[t] = orig;
    __syncthreads();
    for (int d = 1; d < 512; d <<= 1) {
        int u = (t >= d) ? sm[t - d] : 0;
        __syncthreads();
        sm[t] += u;
        __syncthreads();
    }
    if (t < NBS) boff[t] = sm[t] - orig;  // exclusive
}

__global__ void scan_write(const int* __restrict__ deg, const int* __restrict__ boff,
                           int* __restrict__ row_start) {
    __shared__ int sm[256];
    int t = threadIdx.x;
    int i = blockIdx.x * 256 + t;
    int v = (i < kN) ? deg[i] : 0;
    sm[t] = v;
    __syncthreads();
    for (int d = 1; d < 256; d <<= 1) {
        int u = (t >= d) ? sm[t - d] : 0;
        __syncthreads();
        sm[t] += u;
        __syncthreads();
    }
    int excl = sm[t] - v + boff[blockIdx.x];
    if (i < kN) row_start[i] = excl;
    if (i == kN - 1) row_start[kN] = excl + v;
}

__global__ void fill2_kernel(const int* __restrict__ src, const int* __restrict__ dst,
                             const int* __restrict__ row_start,
                             const int* __restrict__ slot, int* __restrict__ srcs) {
    int e = blockIdx.x * blockDim.x + threadIdx.x;
    if (e < kE) srcs[row_start[dst[e]] + slot[e]] = src[e];
}

// ---------------------------------------------------------------------------
// Single-wave fused SAGEConv, 16 nodes/block (64 threads), no __syncthreads.
// R0-proven config (145 us). Established walls (R1-R4): wave packing neutral
// (chip random-line service rate ~22G lines/s is the limiter, invariant to
// occupancy), locality engineering neutral (random graph, reuse spread across
// incoherent XCD L2s). This round's single change: non-temporal hints on the
// pure streams (out stores, srcs loads) so the 25.6MB write-allocate stream
// stops cycling the 4MB XCD L2 and evicting gather-table lines.
// Gather: per 16-lane group, 16 idx prefetched coalesced; 16 row loads
// batched in registers with a sched_barrier(0) pinning ALL loads before the
// consume. (64,4) bound = 128-reg cap.
// MFMA: M=16, K=256 [mean|root], weights hi+lo from L2.
// LDS: [16][136] fp16 = 4352 B/block.
// ---------------------------------------------------------------------------
template <bool RELU>
__global__ __launch_bounds__(64, 4) void conv_mfma(
    const _Float16* __restrict__ xin,
    const int* __restrict__ row_start,
    const int* __restrict__ srcs,
    const _Float16* __restrict__ Wh,  // [128][256]
    const _Float16* __restrict__ We,  // [128][256]
    const float* __restrict__ bias,
    _Float16* __restrict__ out)
{
    __shared__ __align__(16) _Float16 stg[16 * 136];
    const int l = threadIdx.x & 63;
    const int p = l & 15;
    const int q = l >> 4;
    const int tile = blockIdx.x;
    const int c = p * 8;
    const int lbase = l & 48;

    // Group's 4 nodes: n_s = tile*16 + s*4 + q
    int j0[4], j1[4];
#pragma unroll
    for (int s = 0; s < 4; s++) {
        const int n = tile * 16 + s * 4 + q;
        j0[s] = row_start[n];
        j1[s] = row_start[n + 1];
    }
    // Prefetch first 16 neighbor idx per node (srcs padded; guarded).
    int idx16[4];
#pragma unroll
    for (int s = 0; s < 4; s++) {
        const int tA = j0[s] + p;
        const int v  = __builtin_nontemporal_load(&srcs[tA]);
        idx16[s] = (tA < j1[s]) ? v : 0;
    }

#pragma unroll
    for (int s = 0; s < 4; s++) {
        const int cnt = j1[s] - j0[s];
        float facc[8];
#pragma unroll
        for (int u = 0; u < 8; u++) facc[u] = 0.f;

        for (int jc = j0[s]; jc < j1[s]; jc += 16) {
            int myidx;
            if (jc == j0[s]) {
                myidx = idx16[s];
            } else {
                const int tB = jc + p;
                const int v  = __builtin_nontemporal_load(&srcs[tB]);  // padded, safe
                myidx = (tB < j1[s]) ? v : 0;
            }
            half8 rows[16];
#pragma unroll
            for (int i = 0; i < 16; i++) {
                const int sidx = __shfl(myidx, lbase + i);
                rows[i] = *(const half8*)&xin[(size_t)sidx * 128 + c];  // cached: reuse target
            }
            // Pin: every row load issued before any consume (16 KB/wave in flight)
            __builtin_amdgcn_sched_barrier(0);
            const int rem = j1[s] - jc;
#pragma unroll
            for (int i = 0; i < 16; i++) {
                if (i < rem) {
#pragma unroll
                    for (int u = 0; u < 8; u++) facc[u] += (float)rows[i][u];
                }
            }
        }
        const float inv = 1.0f / (float)(cnt > 1 ? cnt : 1);
        half8 hv;
#pragma unroll
        for (int u = 0; u < 8; u++) hv[u] = (_Float16)(facc[u] * inv);
        *(half8*)&stg[(s * 4 + q) * 136 + c] = hv;
    }

    // Root rows, frag-direct (consecutive rows -> fully coalesced, warms the
    // gather table in L2 -> keep cached)
    half8 rt[4];
#pragma unroll
    for (int kt = 0; kt < 4; kt++)
        rt[kt] = *(const half8*)&xin[(size_t)(tile * 16 + p) * 128 + kt * 32 + q * 8];

    // A-frags for mean half (same-wave DS in-order)
    half8 am[4];
#pragma unroll
    for (int kt = 0; kt < 4; kt++)
        am[kt] = *(const half8*)&stg[p * 136 + kt * 32 + q * 8];

    // MFMA: D[16][128] = A[16][256] @ CW[128][256]^T (hi+lo)
    float4v acc[8];
#pragma unroll
    for (int nt = 0; nt < 8; nt++) {
        const float b = bias[nt * 16 + p];
        acc[nt][0] = b; acc[nt][1] = b; acc[nt][2] = b; acc[nt][3] = b;
    }
#pragma unroll
    for (int kt = 0; kt < 8; kt++) {
        const half8 a = (kt < 4) ? am[kt] : rt[kt - 4];
#pragma unroll
        for (int nt = 0; nt < 8; nt++) {
            const int widx = (nt * 16 + p) * 256 + kt * 32 + q * 8;
            const half8 bh = *(const half8*)&Wh[widx];
            const half8 be = *(const half8*)&We[widx];
            acc[nt] = __builtin_amdgcn_mfma_f32_16x16x32_f16(a, bh, acc[nt], 0, 0, 0);
            acc[nt] = __builtin_amdgcn_mfma_f32_16x16x32_f16(a, be, acc[nt], 0, 0, 0);
        }
    }

    // Epilogue: C-layout -> LDS slice -> coalesced row-major NT store
#pragma unroll
    for (int nt = 0; nt < 8; nt++)
#pragma unroll
        for (int r = 0; r < 4; r++) {
            float v = acc[nt][r];
            if (RELU) v = fmaxf(v, 0.f);
            stg[(q * 4 + r) * 136 + nt * 16 + p] = (_Float16)v;
        }
    {
        const int row = l >> 2;
        const int c2  = (l & 3) * 8;
#pragma unroll
        for (int i = 0; i < 4; i++) {
            const half8 v = *(const half8*)&stg[row * 136 + i * 32 + c2];
            __builtin_nontemporal_store(v,
                (half8*)&out[(size_t)(tile * 16 + row) * 128 + i * 32 + c2]);
        }
    }
}

// ---------------------------------------------------------------------------
// Single-wave fused decoder, 32 pairs/block (64 threads), no __syncthreads.
// P1: batched coalesced row gathers with sched_barrier pin (16 loads in
// flight), products -> LDS. L1/L2: MFMA hi-plane weights. L3: dot+reduce.
// NT on the pure streams (pairs loads, outv stores); z gathers stay cached.
// LDS: [32][136] fp16 = 8704 B/block.
// ---------------------------------------------------------------------------
__global__ __launch_bounds__(64, 4) void decoder_mfma(
    const _Float16* __restrict__ z,
    const int* __restrict__ pairs,
    const _Float16* __restrict__ M1h, const float* __restrict__ bm1,
    const _Float16* __restrict__ M2h, const float* __restrict__ bm2,
    const float* __restrict__ Wm3, const float* __restrict__ bm3,
    float* __restrict__ outv)
{
    __shared__ __align__(16) _Float16 buf[32 * 136];
    const int l = threadIdx.x & 63;
    const int p = l & 15;
    const int q = l >> 4;
    const int tile = blockIdx.x;
    const int c = p * 8;

    // P1: hp = z[a]*z[b]; batch all idx loads, then all row loads (2 epochs)
    intx2 ab[8];
#pragma unroll
    for (int it = 0; it < 8; it++)
        ab[it] = __builtin_nontemporal_load(
            (const intx2*)&pairs[(size_t)(tile * 32 + it * 4 + q) * 2]);
    half8 za[8], zb[8];
#pragma unroll
    for (int it = 0; it < 8; it++) {
        za[it] = *(const half8*)&z[(size_t)ab[it][0] * 128 + c];
        zb[it] = *(const half8*)&z[(size_t)ab[it][1] * 128 + c];
    }
    __builtin_amdgcn_sched_barrier(0);
#pragma unroll
    for (int it = 0; it < 8; it++)
        *(half8*)&buf[(it * 4 + q) * 136 + c] = za[it] * zb[it];

    // L1: y1 = relu(hp @ M1^T + bm1), M=32, N=128, K=128
    half8 a1[2][4];
#pragma unroll
    for (int m = 0; m < 2; m++)
#pragma unroll
        for (int kt = 0; kt < 4; kt++)
            a1[m][kt] = *(const half8*)&buf[(m * 16 + p) * 136 + kt * 32 + q * 8];

    float4v acc1[2][8];
#pragma unroll
    for (int nt = 0; nt < 8; nt++) {
        const float b = bm1[nt * 16 + p];
#pragma unroll
        for (int m = 0; m < 2; m++) {
            acc1[m][nt][0] = b; acc1[m][nt][1] = b; acc1[m][nt][2] = b; acc1[m][nt][3] = b;
        }
    }
#pragma unroll
    for (int kt = 0; kt < 4; kt++)
#pragma unroll
        for (int nt = 0; nt < 8; nt++) {
            const half8 bh = *(const half8*)&M1h[(nt * 16 + p) * 128 + kt * 32 + q * 8];
            acc1[0][nt] = __builtin_amdgcn_mfma_f32_16x16x32_f16(a1[0][kt], bh, acc1[0][nt], 0, 0, 0);
            acc1[1][nt] = __builtin_amdgcn_mfma_f32_16x16x32_f16(a1[1][kt], bh, acc1[1][nt], 0, 0, 0);
        }

    // y1 -> LDS (same-wave order: a1 reads already done)
#pragma unroll
    for (int m = 0; m < 2; m++)
#pragma unroll
        for (int nt = 0; nt < 8; nt++)
#pragma unroll
            for (int r = 0; r < 4; r++)
                buf[(m * 16 + q * 4 + r) * 136 + nt * 16 + p] =
                    (_Float16)fmaxf(acc1[m][nt][r], 0.f);

    // L2: y2 = relu(y1 @ M2^T + bm2), N=64, K=128
    half8 a2[2][4];
#pragma unroll
    for (int m = 0; m < 2; m++)
#pragma unroll
        for (int kt = 0; kt < 4; kt++)
            a2[m][kt] = *(const half8*)&buf[(m * 16 + p) * 136 + kt * 32 + q * 8];

    float4v acc2[2][4];
#pragma unroll
    for (int nt = 0; nt < 4; nt++) {
        const float b = bm2[nt * 16 + p];
#pragma unroll
        for (int m = 0; m < 2; m++) {
            acc2[m][nt][0] = b; acc2[m][nt][1] = b; acc2[m][nt][2] = b; acc2[m][nt][3] = b;
        }
    }
#pragma unroll
    for (int kt = 0; kt < 4; kt++)
#pragma unroll
        for (int nt = 0; nt < 4; nt++) {
            const half8 bh = *(const half8*)&M2h[(nt * 16 + p) * 128 + kt * 32 + q * 8];
            acc2[0][nt] = __builtin_amdgcn_mfma_f32_16x16x32_f16(a2[0][kt], bh, acc2[0][nt], 0, 0, 0);
            acc2[1][nt] = __builtin_amdgcn_mfma_f32_16x16x32_f16(a2[1][kt], bh, acc2[1][nt], 0, 0, 0);
        }

    // L3: out = relu(y2) . Wm3 + bm3
    float wm3v[4];
#pragma unroll
    for (int nt = 0; nt < 4; nt++) wm3v[nt] = Wm3[nt * 16 + p];
    const float b3 = bm3[0];
#pragma unroll
    for (int m = 0; m < 2; m++) {
        float part[4];
#pragma unroll
        for (int r = 0; r < 4; r++) part[r] = 0.f;
#pragma unroll
        for (int nt = 0; nt < 4; nt++)
#pragma unroll
            for (int r = 0; r < 4; r++)
                part[r] += fmaxf(acc2[m][nt][r], 0.f) * wm3v[nt];
#pragma unroll
        for (int s = 1; s <= 8; s <<= 1)
#pragma unroll
            for (int r = 0; r < 4; r++) part[r] += __shfl_xor(part[r], s);
        if (p == 0) {
            floatx4 o;
            o[0] = part[0] + b3; o[1] = part[1] + b3;
            o[2] = part[2] + b3; o[3] = part[3] + b3;
            __builtin_nontemporal_store(o, (floatx4*)&outv[tile * 32 + m * 16 + q * 4]);
        }
    }
}

// ---------------------------------------------------------------------------
extern "C" void kernel_launch(void* const* d_in, const int* in_sizes, int n_in,
                              void* d_out, int out_size, void* d_ws, size_t ws_size,
                              hipStream_t stream) {
    const float* x   = (const float*)d_in[0];
    const int*   src = (const int*)d_in[1];
    const int*   dst = src + kE;
    const int*   ep  = (const int*)d_in[2];
    const float* W1l = (const float*)d_in[3];
    const float* b1l = (const float*)d_in[4];
    const float* W1r = (const float*)d_in[5];
    const float* W2l = (const float*)d_in[6];
    const float* b2l = (const float*)d_in[7];
    const float* W2r = (const float*)d_in[8];
    const float* Wm1 = (const float*)d_in[9];
    const float* bm1 = (const float*)d_in[10];
    const float* Wm2 = (const float*)d_in[11];
    const float* bm2 = (const float*)d_in[12];
    const float* Wm3 = (const float*)d_in[13];
    const float* bm3 = (const float*)d_in[14];
    float* outv = (float*)d_out;

    char* ws = (char*)d_ws;
    size_t off = 0;
    auto alloc = [&](size_t bytes) -> void* {
        void* p = ws + off;
        off += bytes;
        off = (off + 255) & ~(size_t)255;
        return p;
    };
    int*      deg       = (int*)alloc((size_t)kN * 4);
    int*      row_start = (int*)alloc((size_t)(kN + 1) * 4);
    int*      slot      = (int*)alloc((size_t)kE * 4);
    int*      bsum      = (int*)alloc(512 * 4);
    int*      boff      = (int*)alloc(512 * 4);
    int*      srcs      = (int*)alloc((size_t)(kE + 64) * 4);  // padded
    _Float16* xh        = (_Float16*)alloc((size_t)kN * 128 * 2);
    _Float16* hh        = (_Float16*)alloc((size_t)kN * 128 * 2);
    _Float16* zh        = (_Float16*)alloc((size_t)kN * 128 * 2);
    _Float16* CW1h      = (_Float16*)alloc(128 * 256 * 2);
    _Float16* CW1e      = (_Float16*)alloc(128 * 256 * 2);
    _Float16* CW2h      = (_Float16*)alloc(128 * 256 * 2);
    _Float16* CW2e      = (_Float16*)alloc(128 * 256 * 2);
    _Float16* M1h       = (_Float16*)alloc(128 * 128 * 2);
    _Float16* M2h       = (_Float16*)alloc(64 * 128 * 2);

    // Fused prep (histogram+slot, cvt_x, cvt_w) + scan + atomic-free fill
    hipMemsetAsync(deg, 0, (size_t)kN * sizeof(int), stream);
    prep_kernel<<<12852, 256, 0, stream>>>(dst, deg, slot, x, xh,
                                           W1l, W1r, W2l, W2r, Wm1, Wm2,
                                           CW1h, CW1e, CW2h, CW2e, M1h, M2h);
    scan_block_sums<<<NBS, 256, 0, stream>>>(deg, bsum);
    scan_bsums<<<1, 512, 0, stream>>>(bsum, boff);
    scan_write<<<NBS, 256, 0, stream>>>(deg, boff, row_start);
    fill2_kernel<<<(kE + 255) / 256, 256, 0, stream>>>(src, dst, row_start, slot, srcs);

    // Two SAGEConv layers (single-wave blocks, pinned 16-row batches)
    conv_mfma<true><<<CT3, 64, 0, stream>>>(xh, row_start, srcs, CW1h, CW1e, b1l, hh);
    conv_mfma<false><<<CT3, 64, 0, stream>>>(hh, row_start, srcs, CW2h, CW2e, b2l, zh);

    // Fused decoder (single-wave blocks, pinned row batch)
    decoder_mfma<<<DT2, 64, 0, stream>>>(
        zh, ep, M1h, bm1, M2h, bm2, Wm3, bm3, outv);
}